// Round 6
// baseline (598.288 us; speedup 1.0000x reference)
//
#include <hip/hip_runtime.h>
#include <hip/hip_bf16.h>
#include <cstddef>

// Problem constants (Qwen3-style attention block, fp32 in/out)
constexpr int B_   = 2;
constexpr int S_   = 2048;
constexpr int D_   = 2048;
constexpr int H_   = 16;
constexpr int HKV_ = 4;
constexpr int HD_  = 128;
constexpr int M_   = B_ * S_;        // 4096 token rows
constexpr int NQKV_ = H_ * HD_ + 2 * HKV_ * HD_;  // 3072 fused QKV cols
constexpr float QSCALE = 0.08838834764831845f;    // 1/sqrt(128)

typedef __attribute__((ext_vector_type(8))) short bs8;   // 8 bf16 (4 VGPR)
typedef __attribute__((ext_vector_type(4))) float fx4;   // MFMA accumulator

// ---------------------------------------------------------------------------
// helpers
// ---------------------------------------------------------------------------
__device__ __forceinline__ void split2(float x, short& hi, short& lo) {
  __hip_bfloat16 h = __float2bfloat16(x);          // RNE
  float hf = __bfloat162float(h);
  __hip_bfloat16 l = __float2bfloat16(x - hf);
  hi = *(short*)&h;
  lo = *(short*)&l;
}

__device__ __forceinline__ void gload16(const short* g, short* l) {
  __builtin_amdgcn_global_load_lds(
      (const __attribute__((address_space(1))) void*)g,
      (__attribute__((address_space(3))) void*)l, 16, 0, 0);
}

__device__ __forceinline__ void bar_raw() {
  asm volatile("s_barrier" ::: "memory");
}
__device__ __forceinline__ void vmwait8() {
  asm volatile("s_waitcnt vmcnt(8)" ::: "memory");
}
__device__ __forceinline__ void vmwait4() {
  asm volatile("s_waitcnt vmcnt(4)" ::: "memory");
}
__device__ __forceinline__ void vmwait0() {
  asm volatile("s_waitcnt vmcnt(0)" ::: "memory");
}

// ---------------------------------------------------------------------------
// Split hidden (M x 2048 fp32) -> Asp (M x 4096 bf16, cols [0,2048)=hi, lo after)
// ---------------------------------------------------------------------------
__global__ __launch_bounds__(256) void split_hidden(
    const float4* __restrict__ X, short* __restrict__ out)
{
  const long i4  = (long)blockIdx.x * 256 + threadIdx.x;
  const long row = i4 >> 9;
  const long c   = (i4 & 511) * 4;
  const float4 v = X[i4];
  short h[4], l[4];
  split2(v.x, h[0], l[0]); split2(v.y, h[1], l[1]);
  split2(v.z, h[2], l[2]); split2(v.w, h[3], l[3]);
  *(short4*)&out[row * 4096 + c]        = make_short4(h[0], h[1], h[2], h[3]);
  *(short4*)&out[row * 4096 + 2048 + c] = make_short4(l[0], l[1], l[2], l[3]);
}

// ---------------------------------------------------------------------------
// Transpose+split weight W (2048 x N fp32) -> out[(row0+n)*4096 + {k | 2048+k}]
// ---------------------------------------------------------------------------
__global__ __launch_bounds__(256) void tsplit(
    const float* __restrict__ W, int N, short* __restrict__ out, int row0)
{
  __shared__ float tile[32][33];
  const int k0 = blockIdx.y * 32;
  const int n0 = blockIdx.x * 32;
  const int x = threadIdx.x, y = threadIdx.y;
  #pragma unroll
  for (int i = 0; i < 4; ++i)
    tile[y + 8 * i][x] = W[(size_t)(k0 + y + 8 * i) * N + n0 + x];
  __syncthreads();
  #pragma unroll
  for (int i = 0; i < 4; ++i) {
    const int n = n0 + y + 8 * i;
    const float v = tile[x][y + 8 * i];
    short hi, lo;
    split2(v, hi, lo);
    out[(size_t)(row0 + n) * 4096 + k0 + x]        = hi;
    out[(size_t)(row0 + n) * 4096 + 2048 + k0 + x] = lo;
  }
}

// ---------------------------------------------------------------------------
// Split-bf16 MFMA GEMM, pipelined:
//   - 128x128 tile, 4 waves, BK=32, virtual K' = 3K (hi*hi | lo*hi | hi*lo)
//   - 3-slot LDS ring (48KB), staged 2 K-steps ahead via global_load_lds
//   - counted s_waitcnt vmcnt(8) + raw s_barrier (no vmcnt(0) drain in loop)
//   - T2 chunk swizzle: LDS [64][64], chunk c = ((row&1)*4+g) ^ ((row>>1)&7);
//     linear LDS dest + inverse-swizzled per-lane GLOBAL source (m173)
//   - 3 blocks/CU: QKV grid 768 = 3*256 exact fill; XCD chunk swizzle
// ---------------------------------------------------------------------------
__global__ __launch_bounds__(256, 3) void gemm_split_bf16(
    const short* __restrict__ Asp, const short* __restrict__ Bsp,
    float* __restrict__ C, int M, int N, int K)
{
  __shared__ __align__(16) short As[3][64 * 64];   // 3 x 8KB
  __shared__ __align__(16) short Bs[3][64 * 64];   // 3 x 8KB

  const int t    = threadIdx.x;
  const int lane = t & 63, wid = t >> 6;
  const int wr   = wid >> 1, wc = wid & 1;

  const int nbx = gridDim.x;
  const int nwg = nbx * gridDim.y;
  int bid = blockIdx.y * nbx + blockIdx.x;
  bid = (bid & 7) * (nwg >> 3) + (bid >> 3);
  const int bm = (bid / nbx) * 128, bn = (bid % nbx) * 128;
  const int ld = 2 * K;

  fx4 acc[4][4] = {};

  // ---- staging geometry: thread t stages chunks {t, t+256} of each 8KB tile.
  // linear LDS chunk p -> (r2 = p>>3, c = p&7); logical chunk lc = c ^ (r2&7);
  // tile row = 2*r2 + (lc>>2), k-chunk = lc&3.
  size_t srcA[2], srcB[2];
  int    ldst[2];
  #pragma unroll
  for (int i = 0; i < 2; ++i) {
    const int p  = t + 256 * i;
    const int r2 = p >> 3;
    const int lc = (p & 7) ^ (r2 & 7);
    const int ro = 2 * r2 + (lc >> 2);
    const int co = (lc & 3) * 8;
    srcA[i] = (size_t)(bm + ro) * ld + co;
    srcB[i] = (size_t)(bn + ro) * ld + co;
    ldst[i] = p * 8;                       // element offset (16B chunk)
  }

  auto stage = [&](int ktile, int slot) {
    const int kp = ktile * 32;
    const int ca = (kp < 2 * K) ? kp : kp - 2 * K;  // A col base (hi|lo|hi)
    const int cb = (kp < K) ? kp : kp - K;          // B col base (hi|hi|lo)
    gload16(Asp + srcA[0] + ca, &As[slot][ldst[0]]);
    gload16(Asp + srcA[1] + ca, &As[slot][ldst[1]]);
    gload16(Bsp + srcB[0] + cb, &Bs[slot][ldst[0]]);
    gload16(Bsp + srcB[1] + cb, &Bs[slot][ldst[1]]);
  };

  // ---- fragment read offsets (swizzled), fixed per thread ----
  const int lr = lane & 15, g = lane >> 4;
  int aofs[4], bofs[4];
  #pragma unroll
  for (int m = 0; m < 4; ++m) {
    const int rowa = wr * 64 + m * 16 + lr;
    aofs[m] = (rowa >> 1) * 64 + (((((rowa & 1) << 2) + g) ^ ((rowa >> 1) & 7)) << 3);
    const int rowb = wc * 64 + m * 16 + lr;
    bofs[m] = (rowb >> 1) * 64 + (((((rowb & 1) << 2) + g) ^ ((rowb >> 1) & 7)) << 3);
  }

  const int ntk = 3 * K / 32;   // 192 K-steps

  stage(0, 0);
  stage(1, 1);

  #pragma unroll 1
  for (int kt = 0; kt < ntk; ++kt) {
    bar_raw();                         // all waves done reading slot (kt+2)%3
    if (kt + 2 < ntk) {
      stage(kt + 2, (kt + 2) % 3);     // post-barrier -> legal overwrite
      vmwait8();                       // own kt loads (2 steps old) landed
    } else if (kt + 1 < ntk) {
      vmwait4();
    } else {
      vmwait0();
    }
    bar_raw();                         // everyone's kt loads landed

    const short* Ac = As[kt % 3];
    const short* Bc = Bs[kt % 3];

    bs8 af[4], bf[4];
    #pragma unroll
    for (int m = 0; m < 4; ++m) af[m] = *(const bs8*)&Ac[aofs[m]];
    #pragma unroll
    for (int n = 0; n < 4; ++n) bf[n] = *(const bs8*)&Bc[bofs[n]];

    __builtin_amdgcn_s_setprio(1);
    #pragma unroll
    for (int m = 0; m < 4; ++m)
      #pragma unroll
      for (int n = 0; n < 4; ++n)
        acc[m][n] = __builtin_amdgcn_mfma_f32_16x16x32_bf16(af[m], bf[n], acc[m][n], 0, 0, 0);
    __builtin_amdgcn_s_setprio(0);
  }

  // epilogue: C/D mapping col=lane&15, row=(lane>>4)*4+reg (m89-verified)
  const int lg = lane >> 4;
  #pragma unroll
  for (int m = 0; m < 4; ++m)
    #pragma unroll
    for (int n = 0; n < 4; ++n) {
      const int col = bn + wc * 64 + n * 16 + lr;
      #pragma unroll
      for (int r = 0; r < 4; ++r) {
        const int row = bm + wr * 64 + m * 16 + lg * 4 + r;
        C[(size_t)row * N + col] = acc[m][n][r];
      }
    }
}

// ---------------------------------------------------------------------------
// Fused RMSNorm + RoPE. Q rows: in-place fp32. K rows: hi/lo bf16 overlay.
// ---------------------------------------------------------------------------
__global__ __launch_bounds__(64) void rmsrope(
    float* __restrict__ qkv, const float* __restrict__ qw,
    const float* __restrict__ kw, const int* __restrict__ pos_ids)
{
  const int row  = blockIdx.x;
  const int lane = threadIdx.x;
  constexpr int NQROWS = M_ * H_;
  const bool isq = row < NQROWS;

  int token; float* ptr; const float* w;
  if (isq) {
    token = row / H_;
    ptr = qkv + (size_t)token * NQKV_ + (row % H_) * HD_;
    w = qw;
  } else {
    const int rk = row - NQROWS;
    token = rk / HKV_;
    ptr = qkv + (size_t)token * NQKV_ + 2048 + (rk % HKV_) * HD_;
    w = kw;
  }

  const float x1 = ptr[lane];
  const float x2 = ptr[lane + 64];
  float ss = x1 * x1 + x2 * x2;
  #pragma unroll
  for (int m = 1; m < 64; m <<= 1) ss += __shfl_xor(ss, m, 64);
  const float rinv = rsqrtf(ss * (1.0f / 128.0f) + 1e-6f);
  const float y1 = x1 * rinv * w[lane];
  const float y2 = x2 * rinv * w[lane + 64];

  const int pos = pos_ids[token];
  const float f = (float)pos * powf(10000.0f, -(float)lane * (1.0f / 64.0f));
  float sn, c;
  sincosf(f, &sn, &c);
  const float o1 = y1 * c - y2 * sn;
  const float o2 = y2 * c + y1 * sn;

  if (isq) {
    ptr[lane]      = o1;
    ptr[lane + 64] = o2;
  } else {
    short* srow = (short*)ptr;
    short h1, l1, h2, l2;
    split2(o1, h1, l1);
    split2(o2, h2, l2);
    srow[lane]       = h1;  srow[lane + 64]  = h2;   // hi[0..127]
    srow[128 + lane] = l1;  srow[192 + lane] = l2;   // lo[0..127]
  }
}

// ---------------------------------------------------------------------------
// V transpose+cast: qkv V region -> Vsp[(b*HKV+kvh)*128 + d][s] bf16 (ld = S)
// ---------------------------------------------------------------------------
__global__ __launch_bounds__(256) void vtrans(
    const float* __restrict__ qkv, short* __restrict__ vsp)
{
  __shared__ float tile[32][33];
  const int by = blockIdx.y;
  const int b = by >> 4, kvh = (by >> 2) & 3, d0 = (by & 3) * 32;
  const int s0 = blockIdx.x * 32;
  const int tx = threadIdx.x, ty = threadIdx.y;
  #pragma unroll
  for (int i = 0; i < 4; ++i)
    tile[ty + 8 * i][tx] =
        qkv[(size_t)(b * S_ + s0 + ty + 8 * i) * NQKV_ + 2560 + kvh * 128 + d0 + tx];
  __syncthreads();
  #pragma unroll
  for (int i = 0; i < 4; ++i) {
    const int d = d0 + ty + 8 * i;
    __hip_bfloat16 v = __float2bfloat16(tile[tx][ty + 8 * i]);
    vsp[((size_t)(b * HKV_ + kvh) * 128 + d) * (size_t)S_ + s0 + tx] = *(short*)&v;
  }
}

// ---------------------------------------------------------------------------
// MFMA causal GQA flash attention v3 (unchanged from round 5, validated).
// ---------------------------------------------------------------------------
__global__ __launch_bounds__(256, 2) void attn_mfma3(
    const float* __restrict__ qkv, const short* __restrict__ vsp,
    short* __restrict__ osp)
{
  __shared__ __align__(16) short Kh[64 * 128];
  __shared__ __align__(16) short Kl[64 * 128];
  __shared__ __align__(16) short Vt[128 * 64];   // [d][j]
  __shared__ __align__(16) short sP[64 * 64];    // [r][j], wave-private rows

  const int t    = threadIdx.x;
  const int lane = t & 63;
  const int w    = t >> 6;        // wave id: rows 16w..16w+15
  const int lr   = lane & 15;
  const int g    = lane >> 4;
  const int p  = blockIdx.x;      // fold pair index 0..15
  const int bh = blockIdx.y;
  const int b = bh >> 4, h = bh & 15;
  const int kvh = h >> 2;
  const int bhk = b * HKV_ + kvh;
  const short* kb = (const short*)qkv;   // K region overlaid bf16 by rmsrope

  bs8 rKh[4], rKl[4], rV[4];

  const short* kbase = kb + (size_t)b * S_ * 6144 + 4096 + kvh * 256;
  const short* vbase = vsp + (size_t)bhk * 128 * (size_t)S_;

  auto stage_load = [&](int k0) {
    #pragma unroll
    for (int i = 0; i < 4; ++i) {
      const int idx = t + 256 * i;
      const int sj = idx >> 4, c = idx & 15;
      rKh[i] = *(const bs8*)(kbase + (size_t)(k0 + sj) * 6144 + 8 * c);
      rKl[i] = *(const bs8*)(kbase + (size_t)(k0 + sj) * 6144 + 128 + 8 * c);
      const int d = idx >> 3, c2 = idx & 7;
      rV[i] = *(const bs8*)(vbase + (size_t)d * S_ + k0 + 8 * c2);
    }
  };
  auto stage_write = [&]() {
    #pragma unroll
    for (int i = 0; i < 4; ++i) {
      const int idx = t + 256 * i;
      const int sj = idx >> 4, c = idx & 15;
      *(bs8*)&Kh[sj * 128 + ((c ^ (sj & 15)) << 3)] = rKh[i];
      *(bs8*)&Kl[sj * 128 + ((c ^ (sj & 15)) << 3)] = rKl[i];
      const int d = idx >> 3, c2 = idx & 7;
      *(bs8*)&Vt[d * 64 + ((c2 ^ (d & 7)) << 3)] = rV[i];
    }
  };

  const int qts[2] = {p, 31 - p};

  #pragma unroll 1
  for (int sg = 0; sg < 2; ++sg) {
    const int qt  = qts[sg];
    const int q0  = 64 * qt;
    const int ntk = qt + 1;

    stage_load(0);

    bs8 qh[4], ql[4];
    {
      const float* qrow =
          qkv + (size_t)(b * S_ + q0 + 16 * w + lr) * NQKV_ + h * HD_ + g * 8;
      #pragma unroll
      for (int dc = 0; dc < 4; ++dc) {
        float x[8];
        *(float4*)&x[0] = *(const float4*)(qrow + 32 * dc);
        *(float4*)&x[4] = *(const float4*)(qrow + 32 * dc + 4);
        #pragma unroll
        for (int e = 0; e < 8; ++e) {
          short hi, lo;
          split2(x[e] * QSCALE, hi, lo);
          qh[dc][e] = hi; ql[dc][e] = lo;
        }
      }
    }

    fx4 o[8] = {};
    float m_i[4] = {-1e30f, -1e30f, -1e30f, -1e30f};
    float l_i[4] = {0.f, 0.f, 0.f, 0.f};

    stage_write();
    __syncthreads();
    if (ntk > 1) stage_load(64);

    #pragma unroll 1
    for (int kt = 0; kt < ntk; ++kt) {
      fx4 s[4] = {};
      __builtin_amdgcn_s_setprio(1);
      #pragma unroll
      for (int dc = 0; dc < 4; ++dc) {
        #pragma unroll
        for (int n = 0; n < 4; ++n) {
          const int ko = (16 * n + lr) * 128 + (((dc * 4 + g) ^ lr) << 3);
          const bs8 fh = *(const bs8*)&Kh[ko];
          const bs8 fl = *(const bs8*)&Kl[ko];
          s[n] = __builtin_amdgcn_mfma_f32_16x16x32_bf16(qh[dc], fh, s[n], 0, 0, 0);
          s[n] = __builtin_amdgcn_mfma_f32_16x16x32_bf16(ql[dc], fh, s[n], 0, 0, 0);
          s[n] = __builtin_amdgcn_mfma_f32_16x16x32_bf16(qh[dc], fl, s[n], 0, 0, 0);
        }
      }
      __builtin_amdgcn_s_setprio(0);

      if (kt == qt) {
        #pragma unroll
        for (int n = 0; n < 4; ++n)
          #pragma unroll
          for (int r = 0; r < 4; ++r)
            if (16 * n + lr > 16 * w + 4 * g + r) s[n][r] = -1e30f;
      }

      #pragma unroll
      for (int r = 0; r < 4; ++r) {
        float rm = fmaxf(fmaxf(s[0][r], s[1][r]), fmaxf(s[2][r], s[3][r]));
        rm = fmaxf(rm, __shfl_xor(rm, 1, 64));
        rm = fmaxf(rm, __shfl_xor(rm, 2, 64));
        rm = fmaxf(rm, __shfl_xor(rm, 4, 64));
        rm = fmaxf(rm, __shfl_xor(rm, 8, 64));
        const float mn    = fmaxf(m_i[r], rm);
        const float alpha = __expf(m_i[r] - mn);
        float ps = 0.f;
        #pragma unroll
        for (int n = 0; n < 4; ++n) {
          const float pv = __expf(s[n][r] - mn);
          s[n][r] = pv;
          ps += pv;
        }
        ps += __shfl_xor(ps, 1, 64);
        ps += __shfl_xor(ps, 2, 64);
        ps += __shfl_xor(ps, 4, 64);
        ps += __shfl_xor(ps, 8, 64);
        l_i[r] = l_i[r] * alpha + ps;
        m_i[r] = mn;
        #pragma unroll
        for (int df = 0; df < 8; ++df) o[df][r] *= alpha;

        const int rr = 16 * w + 4 * g + r;
        #pragma unroll
        for (int n = 0; n < 4; ++n) {
          __hip_bfloat16 pb = __float2bfloat16(s[n][r]);
          sP[rr * 64 + ((((2 * n + (lr >> 3)) ^ (rr & 7))) << 3) + (lr & 7)] = *(short*)&pb;
        }
      }

      const int pro = (16 * w + lr) * 64;
      const bs8 pa0 = *(const bs8*)&sP[pro + (((g)     ^ (lr & 7)) << 3)];
      const bs8 pa1 = *(const bs8*)&sP[pro + (((g + 4) ^ (lr & 7)) << 3)];
      __builtin_amdgcn_s_setprio(1);
      #pragma unroll
      for (int df = 0; df < 8; ++df) {
        const int vo = (16 * df + lr) * 64;
        const bs8 v0 = *(const bs8*)&Vt[vo + (((g)     ^ (lr & 7)) << 3)];
        const bs8 v1 = *(const bs8*)&Vt[vo + (((g + 4) ^ (lr & 7)) << 3)];
        o[df] = __builtin_amdgcn_mfma_f32_16x16x32_bf16(pa0, v0, o[df], 0, 0, 0);
        o[df] = __builtin_amdgcn_mfma_f32_16x16x32_bf16(pa1, v1, o[df], 0, 0, 0);
      }
      __builtin_amdgcn_s_setprio(0);

      __syncthreads();
      if (kt + 1 < ntk) {
        stage_write();
        __syncthreads();
        if (kt + 2 < ntk) stage_load(64 * (kt + 2));
      }
    }

    #pragma unroll
    for (int r = 0; r < 4; ++r) {
      const float inv = 1.0f / l_i[r];
      const size_t ro =
          (size_t)(b * S_ + q0 + 16 * w + 4 * g + r) * 4096 + h * HD_;
      #pragma unroll
      for (int df = 0; df < 8; ++df) {
        short hi, lo;
        split2(o[df][r] * inv, hi, lo);
        osp[ro + 16 * df + lr]        = hi;
        osp[ro + 2048 + 16 * df + lr] = lo;
      }
    }
  }
}

// ---------------------------------------------------------------------------
extern "C" void kernel_launch(void* const* d_in, const int* in_sizes, int n_in,
                              void* d_out, int out_size, void* d_ws, size_t ws_size,
                              hipStream_t stream) {
  const float* hidden = (const float*)d_in[0];
  const float* wq     = (const float*)d_in[1];
  const float* wk     = (const float*)d_in[2];
  const float* wv     = (const float*)d_in[3];
  const float* wo     = (const float*)d_in[4];
  const float* qw     = (const float*)d_in[5];
  const float* kw     = (const float*)d_in[6];
  const int*   pos    = (const int*)d_in[7];
  float*       out    = (float*)d_out;

  // Workspace (104 MB):
  //   R0 [0,32MB): Asp hidden split; reused as Osp (attn-out split)
  //   R1 [32,56MB): Bsp weight splits; rows 2048.. reused as Vsp after QKV GEMM
  //   R2 [56,104MB): qkv fp32 (K region overlaid bf16 hi/lo by rmsrope)
  const size_t aspB = (size_t)M_ * 4096 * 2;
  const size_t bspB = (size_t)NQKV_ * 4096 * 2;
  const size_t qkvB = (size_t)M_ * NQKV_ * 4;
  if (ws_size < aspB + bspB + qkvB) return;   // visible failure

  short* Asp = (short*)d_ws;
  short* Bsp = (short*)((char*)d_ws + aspB);
  float* qkv = (float*)((char*)d_ws + aspB + bspB);
  short* Osp = Asp;
  short* Vsp = Bsp + (size_t)2048 * 4096;   // 4MB inside dead QKV-weight rows

  // 1) precision splits
  split_hidden<<<(M_ * D_ / 4) / 256, 256, 0, stream>>>((const float4*)hidden, Asp);
  tsplit<<<dim3(2048 / 32, 64), dim3(32, 8), 0, stream>>>(wq, 2048, Bsp, 0);
  tsplit<<<dim3(512 / 32, 64),  dim3(32, 8), 0, stream>>>(wk, 512,  Bsp, 2048);
  tsplit<<<dim3(512 / 32, 64),  dim3(32, 8), 0, stream>>>(wv, 512,  Bsp, 2560);

  // 2) fused QKV projection (pipelined split GEMM)
  gemm_split_bf16<<<dim3(NQKV_ / 128, M_ / 128), 256, 0, stream>>>(
      Asp, Bsp, qkv, M_, NQKV_, 2048);

  // 3) RMSNorm + RoPE (Q fp32 in place; K -> bf16 hi/lo in place)
  rmsrope<<<M_ * (H_ + HKV_), 64, 0, stream>>>(qkv, qw, kw, pos);

  // 4) V transpose+cast into Vsp
  vtrans<<<dim3(S_ / 32, 32), dim3(32, 8), 0, stream>>>(qkv, Vsp);

  // 5) MFMA flash attention v3 -> Osp (hi/lo split, ld 4096)
  attn_mfma3<<<dim3(16, B_ * H_), 256, 0, stream>>>(qkv, Vsp, Osp);

  // 6) output projection
  tsplit<<<dim3(2048 / 32, 64), dim3(32, 8), 0, stream>>>(wo, 2048, Bsp, 0);
  gemm_split_bf16<<<dim3(D_ / 128, M_ / 128), 256, 0, stream>>>(
      Osp, Bsp, out, M_, D_, 2048);
}